// Round 4
// baseline (122.419 us; speedup 1.0000x reference)
//
#include <hip/hip_runtime.h>

#define NROWS 2048
#define MLEN  3000
#define LPAD  4096
#define PAD0  548
#define NLVL  8
#define NT    256

union F4 { float4 v; float f[4]; };

// LDS diet: SA 8KB + SB 8KB + CS 2KB + filters 0.5KB = 18.5KB
//  -> 8 blocks/CU resident (148KB LDS, 32 waves) -> grid 2048 = exactly 8/CU, zero tail.
// Level-0 analysis reads the input row directly from global (L1-resident overlapping
// windows) so no 16KB staging buffer is needed. All LDS traffic is b128/b64.
// CS mirrors crow[3584..4096) (details lvl>=3 + final approx) so thin synthesis levels
// never touch global; wide levels (0-2) re-read details from L2 (written this block).
__global__ __launch_bounds__(NT, 8) void despawn_kernel(
    const float* __restrict__ x,
    const float* __restrict__ scaling,
    const float* __restrict__ scaling_rec,
    float* __restrict__ recon_out,
    float* __restrict__ coef_out)
{
    __shared__ __align__(16) float SA[2048];   // 8 KB
    __shared__ __align__(16) float SB[2048];   // 8 KB
    __shared__ __align__(16) float CS[512];    // 2 KB
    __shared__ float fsca[64];
    __shared__ float fwav[64];

    const int tid = threadIdx.x;
    const int row = blockIdx.x;
    float* const crow = coef_out + (size_t)row * LPAD;
    const float* xr = x + (size_t)row * MLEN;

    // wav[k] = scaling_rec[lvl][7-k] * (-1)^k  (_make_wavelet)
    if (tid < 64) {
        const int lvl = tid >> 3, k = tid & 7;
        fsca[tid] = scaling[tid];
        fwav[tid] = scaling_rec[lvl * 8 + (7 - k)] * ((k & 1) ? -1.0f : 1.0f);
    }
    __syncthreads();

    // ---------------- analysis level 0 : global -> (crow, SA) ----------------
    // out[j] = sum_k x_pad[(2j-k) mod 4096] f[k],  x_pad[i] = xr[clamp(i-548)]
    // (only i<0 wraps circularly -> lands in hi edge pad -> xr[2999])
    {
        float W[8], S[8];
#pragma unroll
        for (int k = 0; k < 8; ++k) { W[k] = fwav[k]; S[k] = fsca[k]; }
        for (int t = tid; t < 512; t += NT) {          // 4 outputs per work item
            const int base = 8 * t - 7;                // natural idx of xv[0]
            float xv[14];
#pragma unroll
            for (int r = 0; r < 14; ++r) {
                const int i = base + r;
                int g = i - PAD0;
                g = g < 0 ? 0 : (g > MLEN - 1 ? MLEN - 1 : g);
                if (i < 0) g = MLEN - 1;               // circular wrap into hi pad
                xv[r] = xr[g];
            }
            float ds[4], as[4];
#pragma unroll
            for (int u = 0; u < 4; ++u) {
                float d = 0.f, a = 0.f;
#pragma unroll
                for (int m = 0; m < 4; ++m) {
                    const float vE = xv[2 * u - 2 * m + 7];   // x_pad[2(j0+u-m)]
                    const float vO = xv[2 * u - 2 * m + 6];   // x_pad[2(j0+u-m-1)+1]
                    d = fmaf(vE, W[2 * m], d);
                    d = fmaf(vO, W[2 * m + 1], d);
                    a = fmaf(vE, S[2 * m], a);
                    a = fmaf(vO, S[2 * m + 1], a);
                }
                ds[u] = d; as[u] = a;
            }
            F4 dv; dv.f[0] = ds[0]; dv.f[1] = ds[1]; dv.f[2] = ds[2]; dv.f[3] = ds[3];
            reinterpret_cast<float4*>(crow)[t] = dv.v;       // details0 -> global
            // approx1 (len 2048) -> SA in split layout [evens(1024) | odds(1024)]
            *reinterpret_cast<float2*>(SA + 2 * t)        = make_float2(as[0], as[2]);
            *reinterpret_cast<float2*>(SA + 1024 + 2 * t) = make_float2(as[1], as[3]);
        }
        __syncthreads();
    }

    // ---------------- analysis levels 1..7 : LDS ping-pong ----------------
    // out[j] = sum_m ev[(j-m)&hm]*f[2m] + od[(j-m-1)&hm]*f[2m+1]
    {
        float* cur = SA;
        float* alt = SB;
        int H = 1024;            // output length of this level; input = 2H split
        int coff = 2048;
        for (int lvl = 1; lvl < NLVL; ++lvl) {
            float W[8], S[8];
#pragma unroll
            for (int k = 0; k < 8; ++k) { W[k] = fwav[lvl * 8 + k]; S[k] = fsca[lvl * 8 + k]; }
            const int q = H >> 2;
            const int qm = q - 1;
            const float4* ev4 = reinterpret_cast<const float4*>(cur);
            const float4* od4 = reinterpret_cast<const float4*>(cur + H);
            float4* dst4 = reinterpret_cast<float4*>(crow + coff);
            float4* cs4 = (lvl >= 3) ? reinterpret_cast<float4*>(&CS[coff - 3584]) : nullptr;
            for (int t = tid; t < q; t += NT) {
                F4 Ea, Eb, Oa, Ob;
                Ea.v = ev4[(t - 1) & qm];
                Eb.v = ev4[t];
                Oa.v = od4[(t - 1) & qm];
                Ob.v = od4[t];
                float e[8] = {Ea.f[0],Ea.f[1],Ea.f[2],Ea.f[3],Eb.f[0],Eb.f[1],Eb.f[2],Eb.f[3]};
                float o[8] = {Oa.f[0],Oa.f[1],Oa.f[2],Oa.f[3],Ob.f[0],Ob.f[1],Ob.f[2],Ob.f[3]};
                float ds[4], as[4];
#pragma unroll
                for (int u = 0; u < 4; ++u) {
                    float d = 0.f, a = 0.f;
#pragma unroll
                    for (int m = 0; m < 4; ++m) {
                        const float vE = e[4 + u - m];
                        const float vO = o[3 + u - m];
                        d = fmaf(vE, W[2 * m], d);
                        d = fmaf(vO, W[2 * m + 1], d);
                        a = fmaf(vE, S[2 * m], a);
                        a = fmaf(vO, S[2 * m + 1], a);
                    }
                    ds[u] = d; as[u] = a;
                }
                F4 dv; dv.f[0] = ds[0]; dv.f[1] = ds[1]; dv.f[2] = ds[2]; dv.f[3] = ds[3];
                dst4[t] = dv.v;
                if (cs4) cs4[t] = dv.v;
                *reinterpret_cast<float2*>(alt + 2 * t)            = make_float2(as[0], as[2]);
                *reinterpret_cast<float2*>(alt + (H >> 1) + 2 * t) = make_float2(as[1], as[3]);
            }
            __syncthreads();
            coff += H;
            float* tmp = cur; cur = alt; alt = tmp;
            H >>= 1;
        }
    }

    // final approx (split, 16) is in SB -> natural order to crow tail + CS tail
    if (tid < 16) {
        const float v = SB[((tid & 1) ? 8 : 0) + (tid >> 1)];
        crow[LPAD - 16 + tid] = v;
        CS[496 + tid] = v;
    }
    __syncthreads();

    // ---------------- synthesis levels 7..1 ----------------
    // out[n] = sum_{k≡n mod 2} d[((n+p)/2+m)&lm]*wav[k] + a[..]*sca[k], k=p+2m
    const float* a = &CS[496];
    float* obuf = SA;           // 32->SA,64->SB,128->SA,256->SB,512->SA,1024->SB,2048->SA
    int len = 16;
    for (int lvl = NLVL - 1; lvl >= 1; --lvl) {
        float W[8], S[8];
#pragma unroll
        for (int k = 0; k < 8; ++k) { W[k] = fwav[lvl * 8 + k]; S[k] = fsca[lvl * 8 + k]; }
        const int Mout = len << 1;
        const int doff = LPAD - (LPAD >> lvl);
        const float4* d4 = (lvl >= 3)
            ? reinterpret_cast<const float4*>(&CS[doff - 3584])
            : reinterpret_cast<const float4*>(crow + doff);
        const float4* a4 = reinterpret_cast<const float4*>(a);
        const int gq = Mout >> 3;     // 8 outputs per work item
        const int fm = (len >> 2) - 1;
        for (int g = tid; g < gq; g += NT) {
            F4 Da, Db, Aa, Ab;
            Da.v = d4[g]; Db.v = d4[(g + 1) & fm];
            Aa.v = a4[g]; Ab.v = a4[(g + 1) & fm];
            float dd[8] = {Da.f[0],Da.f[1],Da.f[2],Da.f[3],Db.f[0],Db.f[1],Db.f[2],Db.f[3]};
            float aa[8] = {Aa.f[0],Aa.f[1],Aa.f[2],Aa.f[3],Ab.f[0],Ab.f[1],Ab.f[2],Ab.f[3]};
            float out[8];
#pragma unroll
            for (int u = 0; u < 8; ++u) {
                const int p = u & 1, c = (u + 1) >> 1;
                float s = 0.f;
#pragma unroll
                for (int m = 0; m < 4; ++m) {
                    s = fmaf(dd[c + m], W[p + 2 * m], s);
                    s = fmaf(aa[c + m], S[p + 2 * m], s);
                }
                out[u] = s;
            }
            F4 o0, o1;
            o0.f[0] = out[0]; o0.f[1] = out[1]; o0.f[2] = out[2]; o0.f[3] = out[3];
            o1.f[0] = out[4]; o1.f[1] = out[5]; o1.f[2] = out[6]; o1.f[3] = out[7];
            float4* ob4 = reinterpret_cast<float4*>(obuf + 8 * g);
            ob4[0] = o0.v; ob4[1] = o1.v;
        }
        __syncthreads();
        a = obuf;
        obuf = (obuf == SA) ? SB : SA;
        len = Mout;
    }
    // a == SA (2048 approx)

    // ---------------- synthesis level 0 : straight to recon ----------------
    {
        float W[8], S[8];
#pragma unroll
        for (int k = 0; k < 8; ++k) { W[k] = fwav[k]; S[k] = fsca[k]; }
        const float4* d4 = reinterpret_cast<const float4*>(crow);   // details0 (L2-warm)
        const float4* a4 = reinterpret_cast<const float4*>(a);
        const int fm = (len >> 2) - 1;                              // len == 2048
        float* const ro = recon_out + (size_t)row * MLEN;
        for (int g = tid; g < (LPAD >> 3); g += NT) {
            F4 Da, Db, Aa, Ab;
            Da.v = d4[g]; Db.v = d4[(g + 1) & fm];
            Aa.v = a4[g]; Ab.v = a4[(g + 1) & fm];
            float dd[8] = {Da.f[0],Da.f[1],Da.f[2],Da.f[3],Db.f[0],Db.f[1],Db.f[2],Db.f[3]};
            float aa[8] = {Aa.f[0],Aa.f[1],Aa.f[2],Aa.f[3],Ab.f[0],Ab.f[1],Ab.f[2],Ab.f[3]};
            float out[8];
#pragma unroll
            for (int u = 0; u < 8; ++u) {
                const int p = u & 1, c = (u + 1) >> 1;
                float s = 0.f;
#pragma unroll
                for (int m = 0; m < 4; ++m) {
                    s = fmaf(dd[c + m], W[p + 2 * m], s);
                    s = fmaf(aa[c + m], S[p + 2 * m], s);
                }
                out[u] = s;
            }
            const int n0 = 8 * g;
            if (n0 >= PAD0 && n0 + 8 <= PAD0 + MLEN) {
                F4 o0, o1;
                o0.f[0] = out[0]; o0.f[1] = out[1]; o0.f[2] = out[2]; o0.f[3] = out[3];
                o1.f[0] = out[4]; o1.f[1] = out[5]; o1.f[2] = out[6]; o1.f[7 - 4] = out[7];
                float4* r4 = reinterpret_cast<float4*>(ro + (n0 - PAD0));
                r4[0] = o0.v; r4[1] = o1.v;
            } else {
#pragma unroll
                for (int u = 0; u < 8; ++u) {
                    const int n = n0 + u;
                    if (n >= PAD0 && n < PAD0 + MLEN) ro[n - PAD0] = out[u];
                }
            }
        }
    }
}

extern "C" void kernel_launch(void* const* d_in, const int* in_sizes, int n_in,
                              void* d_out, int out_size, void* d_ws, size_t ws_size,
                              hipStream_t stream) {
    const float* x           = (const float*)d_in[0];
    const float* scaling     = (const float*)d_in[1];
    const float* scaling_rec = (const float*)d_in[2];
    float* recon = (float*)d_out;                       // 2048*3000 floats
    float* coefo = recon + (size_t)NROWS * MLEN;        // 2048*4096 floats
    despawn_kernel<<<dim3(NROWS), dim3(NT), 0, stream>>>(x, scaling, scaling_rec,
                                                         recon, coefo);
    (void)in_sizes; (void)n_in; (void)out_size; (void)d_ws; (void)ws_size;
}

// Round 5
// 100.915 us; speedup vs baseline: 1.2131x; 1.2131x over previous
//
#include <hip/hip_runtime.h>

#define NROWS 2048
#define MLEN  3000
#define LPAD  4096
#define PAD0  548
#define NLVL  8
#define NT    256

union F4 { float4 v; float f[4]; };

// LDS 19KB (SA 8K + SB 8.5K + CS 2K + filters 0.5K) -> 8 blocks/CU, 32 waves.
// Level-0 input staged through SB in two halves: coalesced float4 global reads,
// split-layout ([ev|od]) LDS, contiguous b128 compute reads (R4's direct-global
// scalar gather cost ~12us of uncoalesced L1 transactions -- reverted).
// Detail mirrors in LDS so synthesis lvl>=1 never reads global:
//   lvl>=3 -> CS[coff-3584], lvl2 -> SA[512..1024), lvl1 -> SB[1088..2112)
// (regions verified dead at those phases in both ping-pong schedules).
__global__ __launch_bounds__(NT, 8) void despawn_kernel(
    const float* __restrict__ x,
    const float* __restrict__ scaling,
    const float* __restrict__ scaling_rec,
    float* __restrict__ recon_out,
    float* __restrict__ coef_out)
{
    __shared__ __align__(16) float SA[2048];   // 8 KB
    __shared__ __align__(16) float SB[2176];   // 8.5 KB (staging needs 2116)
    __shared__ __align__(16) float CS[512];    // 2 KB: details lvl>=3 + final approx
    __shared__ float fsca[64];
    __shared__ float fwav[64];

    const int tid = threadIdx.x;
    const int row = blockIdx.x;
    float* const crow = coef_out + (size_t)row * LPAD;
    const float* xr = x + (size_t)row * MLEN;

    // wav[k] = scaling_rec[lvl][7-k] * (-1)^k   (_make_wavelet)
    if (tid < 64) {
        const int lvl = tid >> 3, k = tid & 7;
        fsca[tid] = scaling[tid];
        fwav[tid] = scaling_rec[lvl * 8 + (7 - k)] * ((k & 1) ? -1.0f : 1.0f);
    }

    // ---------------- analysis level 0 : two halves through SB ----------------
    // out[j] = sum_k x_pad[(2j-k) mod 4096] f[k]; x_pad[i]=xr[clamp(i-548)], i<0 wraps->xhi
    for (int h = 0; h < 2; ++h) {
        const int j0 = 1024 * h;
        // stage naturals [2*j0-8, 2*j0+2048): ev[c]=x_pad[2(j0+c)] at SB[4+c],
        // od[c]=x_pad[2(j0+c)+1] at SB[1088+4+c], c in [-4,1024). group gi: n0=2j0-8+4gi.
        for (int gi = tid; gi < 514; gi += NT) {
            const int n0 = 2 * j0 - 8 + 4 * gi;
            F4 u;
            if (n0 >= PAD0 && n0 + 3 <= PAD0 + MLEN - 1) {
                u.v = *reinterpret_cast<const float4*>(xr + (n0 - PAD0));
            } else {
#pragma unroll
                for (int e = 0; e < 4; ++e) {
                    int n = n0 + e;
                    if (n < 0) n += LPAD;                 // circular wrap into hi pad
                    int g = n - PAD0;
                    g = g < 0 ? 0 : (g > MLEN - 1 ? MLEN - 1 : g);
                    u.f[e] = xr[g];
                }
            }
            *reinterpret_cast<float2*>(&SB[2 * gi])        = make_float2(u.f[0], u.f[2]);
            *reinterpret_cast<float2*>(&SB[1088 + 2 * gi]) = make_float2(u.f[1], u.f[3]);
        }
        __syncthreads();
        {
            float W[8], S[8];
#pragma unroll
            for (int k = 0; k < 8; ++k) { W[k] = fwav[k]; S[k] = fsca[k]; }
            const float4* ev4 = reinterpret_cast<const float4*>(&SB[0]);
            const float4* od4 = reinterpret_cast<const float4*>(&SB[1088]);
            float4* dst4 = reinterpret_cast<float4*>(crow + j0);
            const int t = tid;                 // 256 items, 4 outputs each (j=j0+4t+u)
            F4 Ea, Eb, Oa, Ob;
            Ea.v = ev4[t];     // ev c = 4t-4..4t-1
            Eb.v = ev4[t + 1]; // ev c = 4t..4t+3
            Oa.v = od4[t];
            Ob.v = od4[t + 1];
            float e[8] = {Ea.f[0],Ea.f[1],Ea.f[2],Ea.f[3],Eb.f[0],Eb.f[1],Eb.f[2],Eb.f[3]};
            float o[8] = {Oa.f[0],Oa.f[1],Oa.f[2],Oa.f[3],Ob.f[0],Ob.f[1],Ob.f[2],Ob.f[3]};
            float ds[4], as[4];
#pragma unroll
            for (int u = 0; u < 4; ++u) {
                float d = 0.f, a = 0.f;
#pragma unroll
                for (int m = 0; m < 4; ++m) {
                    const float vE = e[4 + u - m];   // ev[4t+u-m]
                    const float vO = o[3 + u - m];   // od[4t+u-m-1]
                    d = fmaf(vE, W[2 * m], d);
                    d = fmaf(vO, W[2 * m + 1], d);
                    a = fmaf(vE, S[2 * m], a);
                    a = fmaf(vO, S[2 * m + 1], a);
                }
                ds[u] = d; as[u] = a;
            }
            F4 dv; dv.f[0] = ds[0]; dv.f[1] = ds[1]; dv.f[2] = ds[2]; dv.f[3] = ds[3];
            dst4[t] = dv.v;                                  // details0 -> global
            // approx1 -> SA split [ev 0..1024 | od 1024..2048]
            *reinterpret_cast<float2*>(SA + (j0 >> 1) + 2 * t)        = make_float2(as[0], as[2]);
            *reinterpret_cast<float2*>(SA + 1024 + (j0 >> 1) + 2 * t) = make_float2(as[1], as[3]);
        }
        __syncthreads();
    }

    // ---------------- analysis levels 1..7 : LDS ping-pong ----------------
    {
        float* cur = SA;
        float* alt = SB;
        int H = 1024;
        int coff = 2048;
        for (int lvl = 1; lvl < NLVL; ++lvl) {
            float W[8], S[8];
#pragma unroll
            for (int k = 0; k < 8; ++k) { W[k] = fwav[lvl * 8 + k]; S[k] = fsca[lvl * 8 + k]; }
            const int q = H >> 2;
            const int qm = q - 1;
            const float4* ev4 = reinterpret_cast<const float4*>(cur);
            const float4* od4 = reinterpret_cast<const float4*>(cur + H);
            float4* dst4 = reinterpret_cast<float4*>(crow + coff);
            float4* mir4 = (lvl == 1) ? reinterpret_cast<float4*>(&SB[1088])
                         : (lvl == 2) ? reinterpret_cast<float4*>(&SA[512])
                                      : reinterpret_cast<float4*>(&CS[coff - 3584]);
            for (int t = tid; t < q; t += NT) {
                F4 Ea, Eb, Oa, Ob;
                Ea.v = ev4[(t - 1) & qm];
                Eb.v = ev4[t];
                Oa.v = od4[(t - 1) & qm];
                Ob.v = od4[t];
                float e[8] = {Ea.f[0],Ea.f[1],Ea.f[2],Ea.f[3],Eb.f[0],Eb.f[1],Eb.f[2],Eb.f[3]};
                float o[8] = {Oa.f[0],Oa.f[1],Oa.f[2],Oa.f[3],Ob.f[0],Ob.f[1],Ob.f[2],Ob.f[3]};
                float ds[4], as[4];
#pragma unroll
                for (int u = 0; u < 4; ++u) {
                    float d = 0.f, a = 0.f;
#pragma unroll
                    for (int m = 0; m < 4; ++m) {
                        const float vE = e[4 + u - m];
                        const float vO = o[3 + u - m];
                        d = fmaf(vE, W[2 * m], d);
                        d = fmaf(vO, W[2 * m + 1], d);
                        a = fmaf(vE, S[2 * m], a);
                        a = fmaf(vO, S[2 * m + 1], a);
                    }
                    ds[u] = d; as[u] = a;
                }
                F4 dv; dv.f[0] = ds[0]; dv.f[1] = ds[1]; dv.f[2] = ds[2]; dv.f[3] = ds[3];
                dst4[t] = dv.v;      // details -> global (coeffs output)
                mir4[t] = dv.v;      // details -> LDS mirror for synthesis
                *reinterpret_cast<float2*>(alt + 2 * t)            = make_float2(as[0], as[2]);
                *reinterpret_cast<float2*>(alt + (H >> 1) + 2 * t) = make_float2(as[1], as[3]);
            }
            __syncthreads();
            coff += H;
            float* tmp = cur; cur = alt; alt = tmp;
            H >>= 1;
        }
    }

    // final approx (split, 16) in SB -> natural order to crow tail + CS tail
    if (tid < 16) {
        const float v = SB[((tid & 1) ? 8 : 0) + (tid >> 1)];
        crow[LPAD - 16 + tid] = v;
        CS[496 + tid] = v;
    }
    __syncthreads();

    // ---------------- synthesis levels 7..1 (all-LDS) ----------------
    // out[n] = sum_{k≡n mod 2} d[((n+p)/2+m)&lm]*wav[k] + a[..]*sca[k], k=p+2m
    const float* a = &CS[496];
    float* obuf = SA;   // 32->SA,64->SB,128->SA,256->SB,512->SA,1024->SB,2048->SA
    int len = 16;
    for (int lvl = NLVL - 1; lvl >= 1; --lvl) {
        float W[8], S[8];
#pragma unroll
        for (int k = 0; k < 8; ++k) { W[k] = fwav[lvl * 8 + k]; S[k] = fsca[lvl * 8 + k]; }
        const int Mout = len << 1;
        const int doff = LPAD - (LPAD >> lvl);
        const float4* d4 = (lvl >= 3) ? reinterpret_cast<const float4*>(&CS[doff - 3584])
                         : (lvl == 2) ? reinterpret_cast<const float4*>(&SA[512])
                                      : reinterpret_cast<const float4*>(&SB[1088]);
        const float4* a4 = reinterpret_cast<const float4*>(a);
        const int gq = Mout >> 3;     // 8 outputs per work item
        const int fm = (len >> 2) - 1;
        for (int g = tid; g < gq; g += NT) {
            F4 Da, Db, Aa, Ab;
            Da.v = d4[g]; Db.v = d4[(g + 1) & fm];
            Aa.v = a4[g]; Ab.v = a4[(g + 1) & fm];
            float dd[8] = {Da.f[0],Da.f[1],Da.f[2],Da.f[3],Db.f[0],Db.f[1],Db.f[2],Db.f[3]};
            float aa[8] = {Aa.f[0],Aa.f[1],Aa.f[2],Aa.f[3],Ab.f[0],Ab.f[1],Ab.f[2],Ab.f[3]};
            float out[8];
#pragma unroll
            for (int u = 0; u < 8; ++u) {
                const int p = u & 1, c = (u + 1) >> 1;
                float s = 0.f;
#pragma unroll
                for (int m = 0; m < 4; ++m) {
                    s = fmaf(dd[c + m], W[p + 2 * m], s);
                    s = fmaf(aa[c + m], S[p + 2 * m], s);
                }
                out[u] = s;
            }
            F4 o0, o1;
            o0.f[0] = out[0]; o0.f[1] = out[1]; o0.f[2] = out[2]; o0.f[3] = out[3];
            o1.f[0] = out[4]; o1.f[1] = out[5]; o1.f[2] = out[6]; o1.f[3] = out[7];
            float4* ob4 = reinterpret_cast<float4*>(obuf + 8 * g);
            ob4[0] = o0.v; ob4[1] = o1.v;
        }
        __syncthreads();
        a = obuf;
        obuf = (obuf == SA) ? SB : SA;
        len = Mout;
    }
    // a == SA (2048 approx)

    // ---------------- synthesis level 0 : straight to recon ----------------
    {
        float W[8], S[8];
#pragma unroll
        for (int k = 0; k < 8; ++k) { W[k] = fwav[k]; S[k] = fsca[k]; }
        const float4* d4 = reinterpret_cast<const float4*>(crow);   // details0 (L2-warm)
        const float4* a4 = reinterpret_cast<const float4*>(a);
        const int fm = (len >> 2) - 1;                              // len == 2048
        float* const ro = recon_out + (size_t)row * MLEN;
        for (int g = tid; g < (LPAD >> 3); g += NT) {
            F4 Da, Db, Aa, Ab;
            Da.v = d4[g]; Db.v = d4[(g + 1) & fm];
            Aa.v = a4[g]; Ab.v = a4[(g + 1) & fm];
            float dd[8] = {Da.f[0],Da.f[1],Da.f[2],Da.f[3],Db.f[0],Db.f[1],Db.f[2],Db.f[3]};
            float aa[8] = {Aa.f[0],Aa.f[1],Aa.f[2],Aa.f[3],Ab.f[0],Ab.f[1],Ab.f[2],Ab.f[3]};
            float out[8];
#pragma unroll
            for (int u = 0; u < 8; ++u) {
                const int p = u & 1, c = (u + 1) >> 1;
                float s = 0.f;
#pragma unroll
                for (int m = 0; m < 4; ++m) {
                    s = fmaf(dd[c + m], W[p + 2 * m], s);
                    s = fmaf(aa[c + m], S[p + 2 * m], s);
                }
                out[u] = s;
            }
            const int n0 = 8 * g;
            if (n0 >= PAD0 && n0 + 8 <= PAD0 + MLEN) {
                F4 o0, o1;
                o0.f[0] = out[0]; o0.f[1] = out[1]; o0.f[2] = out[2]; o0.f[3] = out[3];
                o1.f[0] = out[4]; o1.f[1] = out[5]; o1.f[2] = out[6]; o1.f[3] = out[7];
                float4* r4 = reinterpret_cast<float4*>(ro + (n0 - PAD0));
                r4[0] = o0.v; r4[1] = o1.v;
            } else {
#pragma unroll
                for (int u = 0; u < 8; ++u) {
                    const int n = n0 + u;
                    if (n >= PAD0 && n < PAD0 + MLEN) ro[n - PAD0] = out[u];
                }
            }
        }
    }
}

extern "C" void kernel_launch(void* const* d_in, const int* in_sizes, int n_in,
                              void* d_out, int out_size, void* d_ws, size_t ws_size,
                              hipStream_t stream) {
    const float* x           = (const float*)d_in[0];
    const float* scaling     = (const float*)d_in[1];
    const float* scaling_rec = (const float*)d_in[2];
    float* recon = (float*)d_out;                       // 2048*3000 floats
    float* coefo = recon + (size_t)NROWS * MLEN;        // 2048*4096 floats
    despawn_kernel<<<dim3(NROWS), dim3(NT), 0, stream>>>(x, scaling, scaling_rec,
                                                         recon, coefo);
    (void)in_sizes; (void)n_in; (void)out_size; (void)d_ws; (void)ws_size;
}

// Round 6
// 99.392 us; speedup vs baseline: 1.2317x; 1.0153x over previous
//
#include <hip/hip_runtime.h>

#define NROWS 2048
#define MLEN  3000
#define LPAD  4096
#define PAD0  548
#define NLVL  8
#define NT    256

union F4 { float4 v; float f[4]; };

// Light barrier: LDS-visibility only (s_waitcnt lgkmcnt(0) + s_barrier), the
// composable_kernel block_sync_lds() idiom. Unlike __syncthreads() it does NOT
// drain vmcnt, so the details->global write-through stays in flight across
// analysis level boundaries (the R1-R5 kernels stalled every phase on
// s_waitcnt vmcnt(0) before s_barrier, in lockstep across all resident blocks).
__device__ inline void lds_barrier() {
    asm volatile("s_waitcnt lgkmcnt(0)\n\ts_barrier" ::: "memory");
}

// LDS 19KB (SA 8K + SB 8.5K + CS 2K + filters 0.5K) -> 8 blocks/CU, 32 waves.
// Coalesced two-half staging through SB; split-layout ([ev|od]) b128 LDS compute.
// Detail mirrors so synthesis lvl>=1 never reads global:
//   lvl>=3 -> CS[coff-3584], lvl2 -> SA[512..1024), lvl1 -> SB[1088..2112)
// (regions verified dead at those phases in both ping-pong schedules).
__global__ __launch_bounds__(NT, 8) void despawn_kernel(
    const float* __restrict__ x,
    const float* __restrict__ scaling,
    const float* __restrict__ scaling_rec,
    float* __restrict__ recon_out,
    float* __restrict__ coef_out)
{
    __shared__ __align__(16) float SA[2048];   // 8 KB
    __shared__ __align__(16) float SB[2176];   // 8.5 KB (staging needs 2116)
    __shared__ __align__(16) float CS[512];    // 2 KB: details lvl>=3 + final approx
    __shared__ float fsca[64];
    __shared__ float fwav[64];

    const int tid = threadIdx.x;
    const int row = blockIdx.x;
    float* const crow = coef_out + (size_t)row * LPAD;
    const float* xr = x + (size_t)row * MLEN;

    // Desync co-resident blocks (CU-mates are blockIdx stride-8: consecutive ids
    // round-robin across the 8 XCDs). Breaks barrier lockstep so one block's
    // phase-latency overlaps another's compute. ~0-1.5K cyc, 4-way stagger.
    {
        const int lag = (blockIdx.x >> 3) & 3;
        for (int i = 0; i < lag; ++i) __builtin_amdgcn_s_sleep(8);
    }

    // wav[k] = scaling_rec[lvl][7-k] * (-1)^k   (_make_wavelet)
    if (tid < 64) {
        const int lvl = tid >> 3, k = tid & 7;
        fsca[tid] = scaling[tid];
        fwav[tid] = scaling_rec[lvl * 8 + (7 - k)] * ((k & 1) ? -1.0f : 1.0f);
    }

    // ---------------- analysis level 0 : two halves through SB ----------------
    // out[j] = sum_k x_pad[(2j-k) mod 4096] f[k]; x_pad[i]=xr[clamp(i-548)], i<0 wraps->xhi
    for (int h = 0; h < 2; ++h) {
        const int j0 = 1024 * h;
        // stage naturals [2*j0-8, 2*j0+2048): ev[c] at SB[4+c], od[c] at SB[1088+4+c]
        for (int gi = tid; gi < 514; gi += NT) {
            const int n0 = 2 * j0 - 8 + 4 * gi;
            F4 u;
            if (n0 >= PAD0 && n0 + 3 <= PAD0 + MLEN - 1) {
                u.v = *reinterpret_cast<const float4*>(xr + (n0 - PAD0));
            } else {
#pragma unroll
                for (int e = 0; e < 4; ++e) {
                    int n = n0 + e;
                    if (n < 0) n += LPAD;                 // circular wrap into hi pad
                    int g = n - PAD0;
                    g = g < 0 ? 0 : (g > MLEN - 1 ? MLEN - 1 : g);
                    u.f[e] = xr[g];
                }
            }
            *reinterpret_cast<float2*>(&SB[2 * gi])        = make_float2(u.f[0], u.f[2]);
            *reinterpret_cast<float2*>(&SB[1088 + 2 * gi]) = make_float2(u.f[1], u.f[3]);
        }
        lds_barrier();
        {
            float W[8], S[8];
#pragma unroll
            for (int k = 0; k < 8; ++k) { W[k] = fwav[k]; S[k] = fsca[k]; }
            const float4* ev4 = reinterpret_cast<const float4*>(&SB[0]);
            const float4* od4 = reinterpret_cast<const float4*>(&SB[1088]);
            float4* dst4 = reinterpret_cast<float4*>(crow + j0);
            const int t = tid;                 // 256 items, 4 outputs each
            F4 Ea, Eb, Oa, Ob;
            Ea.v = ev4[t];     // ev c = 4t-4..4t-1
            Eb.v = ev4[t + 1]; // ev c = 4t..4t+3
            Oa.v = od4[t];
            Ob.v = od4[t + 1];
            float e[8] = {Ea.f[0],Ea.f[1],Ea.f[2],Ea.f[3],Eb.f[0],Eb.f[1],Eb.f[2],Eb.f[3]};
            float o[8] = {Oa.f[0],Oa.f[1],Oa.f[2],Oa.f[3],Ob.f[0],Ob.f[1],Ob.f[2],Ob.f[3]};
            float ds[4], as[4];
#pragma unroll
            for (int u = 0; u < 4; ++u) {
                float d = 0.f, a = 0.f;
#pragma unroll
                for (int m = 0; m < 4; ++m) {
                    const float vE = e[4 + u - m];
                    const float vO = o[3 + u - m];
                    d = fmaf(vE, W[2 * m], d);
                    d = fmaf(vO, W[2 * m + 1], d);
                    a = fmaf(vE, S[2 * m], a);
                    a = fmaf(vO, S[2 * m + 1], a);
                }
                ds[u] = d; as[u] = a;
            }
            F4 dv; dv.f[0] = ds[0]; dv.f[1] = ds[1]; dv.f[2] = ds[2]; dv.f[3] = ds[3];
            dst4[t] = dv.v;                                  // details0 -> global
            *reinterpret_cast<float2*>(SA + (j0 >> 1) + 2 * t)        = make_float2(as[0], as[2]);
            *reinterpret_cast<float2*>(SA + 1024 + (j0 >> 1) + 2 * t) = make_float2(as[1], as[3]);
        }
        lds_barrier();
    }

    // ---------------- analysis levels 1..7 : LDS ping-pong ----------------
    {
        float* cur = SA;
        float* alt = SB;
        int H = 1024;
        int coff = 2048;
        for (int lvl = 1; lvl < NLVL; ++lvl) {
            float W[8], S[8];
#pragma unroll
            for (int k = 0; k < 8; ++k) { W[k] = fwav[lvl * 8 + k]; S[k] = fsca[lvl * 8 + k]; }
            const int q = H >> 2;
            const int qm = q - 1;
            const float4* ev4 = reinterpret_cast<const float4*>(cur);
            const float4* od4 = reinterpret_cast<const float4*>(cur + H);
            float4* dst4 = reinterpret_cast<float4*>(crow + coff);
            float4* mir4 = (lvl == 1) ? reinterpret_cast<float4*>(&SB[1088])
                         : (lvl == 2) ? reinterpret_cast<float4*>(&SA[512])
                                      : reinterpret_cast<float4*>(&CS[coff - 3584]);
            for (int t = tid; t < q; t += NT) {
                F4 Ea, Eb, Oa, Ob;
                Ea.v = ev4[(t - 1) & qm];
                Eb.v = ev4[t];
                Oa.v = od4[(t - 1) & qm];
                Ob.v = od4[t];
                float e[8] = {Ea.f[0],Ea.f[1],Ea.f[2],Ea.f[3],Eb.f[0],Eb.f[1],Eb.f[2],Eb.f[3]};
                float o[8] = {Oa.f[0],Oa.f[1],Oa.f[2],Oa.f[3],Ob.f[0],Ob.f[1],Ob.f[2],Ob.f[3]};
                float ds[4], as[4];
#pragma unroll
                for (int u = 0; u < 4; ++u) {
                    float d = 0.f, a = 0.f;
#pragma unroll
                    for (int m = 0; m < 4; ++m) {
                        const float vE = e[4 + u - m];
                        const float vO = o[3 + u - m];
                        d = fmaf(vE, W[2 * m], d);
                        d = fmaf(vO, W[2 * m + 1], d);
                        a = fmaf(vE, S[2 * m], a);
                        a = fmaf(vO, S[2 * m + 1], a);
                    }
                    ds[u] = d; as[u] = a;
                }
                F4 dv; dv.f[0] = ds[0]; dv.f[1] = ds[1]; dv.f[2] = ds[2]; dv.f[3] = ds[3];
                dst4[t] = dv.v;      // details -> global (coeffs output), not drained
                mir4[t] = dv.v;      // details -> LDS mirror for synthesis
                *reinterpret_cast<float2*>(alt + 2 * t)            = make_float2(as[0], as[2]);
                *reinterpret_cast<float2*>(alt + (H >> 1) + 2 * t) = make_float2(as[1], as[3]);
            }
            lds_barrier();
            coff += H;
            float* tmp = cur; cur = alt; alt = tmp;
            H >>= 1;
        }
    }

    // final approx (split, 16) in SB -> natural order to crow tail + CS tail
    if (tid < 16) {
        const float v = SB[((tid & 1) ? 8 : 0) + (tid >> 1)];
        crow[LPAD - 16 + tid] = v;
        CS[496 + tid] = v;
    }
    // FULL sync: drains every wave's crow stores before synthesis's global
    // readback of details0 (the one place vmcnt(0) is semantically required).
    __syncthreads();

    // ---------------- synthesis levels 7..1 (all-LDS) ----------------
    // out[n] = sum_{k≡n mod 2} d[((n+p)/2+m)&lm]*wav[k] + a[..]*sca[k], k=p+2m
    const float* a = &CS[496];
    float* obuf = SA;   // 32->SA,64->SB,128->SA,256->SB,512->SA,1024->SB,2048->SA
    int len = 16;
    for (int lvl = NLVL - 1; lvl >= 1; --lvl) {
        float W[8], S[8];
#pragma unroll
        for (int k = 0; k < 8; ++k) { W[k] = fwav[lvl * 8 + k]; S[k] = fsca[lvl * 8 + k]; }
        const int Mout = len << 1;
        const int doff = LPAD - (LPAD >> lvl);
        const float4* d4 = (lvl >= 3) ? reinterpret_cast<const float4*>(&CS[doff - 3584])
                         : (lvl == 2) ? reinterpret_cast<const float4*>(&SA[512])
                                      : reinterpret_cast<const float4*>(&SB[1088]);
        const float4* a4 = reinterpret_cast<const float4*>(a);
        const int gq = Mout >> 3;     // 8 outputs per work item
        const int fm = (len >> 2) - 1;
        for (int g = tid; g < gq; g += NT) {
            F4 Da, Db, Aa, Ab;
            Da.v = d4[g]; Db.v = d4[(g + 1) & fm];
            Aa.v = a4[g]; Ab.v = a4[(g + 1) & fm];
            float dd[8] = {Da.f[0],Da.f[1],Da.f[2],Da.f[3],Db.f[0],Db.f[1],Db.f[2],Db.f[3]};
            float aa[8] = {Aa.f[0],Aa.f[1],Aa.f[2],Aa.f[3],Ab.f[0],Ab.f[1],Ab.f[2],Ab.f[3]};
            float out[8];
#pragma unroll
            for (int u = 0; u < 8; ++u) {
                const int p = u & 1, c = (u + 1) >> 1;
                float s = 0.f;
#pragma unroll
                for (int m = 0; m < 4; ++m) {
                    s = fmaf(dd[c + m], W[p + 2 * m], s);
                    s = fmaf(aa[c + m], S[p + 2 * m], s);
                }
                out[u] = s;
            }
            F4 o0, o1;
            o0.f[0] = out[0]; o0.f[1] = out[1]; o0.f[2] = out[2]; o0.f[3] = out[3];
            o1.f[0] = out[4]; o1.f[1] = out[5]; o1.f[2] = out[6]; o1.f[3] = out[7];
            float4* ob4 = reinterpret_cast<float4*>(obuf + 8 * g);
            ob4[0] = o0.v; ob4[1] = o1.v;
        }
        lds_barrier();
        a = obuf;
        obuf = (obuf == SA) ? SB : SA;
        len = Mout;
    }
    // a == SA (2048 approx)

    // ---------------- synthesis level 0 : straight to recon ----------------
    {
        float W[8], S[8];
#pragma unroll
        for (int k = 0; k < 8; ++k) { W[k] = fwav[k]; S[k] = fsca[k]; }
        const float4* d4 = reinterpret_cast<const float4*>(crow);   // details0 (L2-warm)
        const float4* a4 = reinterpret_cast<const float4*>(a);
        const int fm = (len >> 2) - 1;                              // len == 2048
        float* const ro = recon_out + (size_t)row * MLEN;
        for (int g = tid; g < (LPAD >> 3); g += NT) {
            F4 Da, Db, Aa, Ab;
            Da.v = d4[g]; Db.v = d4[(g + 1) & fm];
            Aa.v = a4[g]; Ab.v = a4[(g + 1) & fm];
            float dd[8] = {Da.f[0],Da.f[1],Da.f[2],Da.f[3],Db.f[0],Db.f[1],Db.f[2],Db.f[3]};
            float aa[8] = {Aa.f[0],Aa.f[1],Aa.f[2],Aa.f[3],Ab.f[0],Ab.f[1],Ab.f[2],Ab.f[3]};
            float out[8];
#pragma unroll
            for (int u = 0; u < 8; ++u) {
                const int p = u & 1, c = (u + 1) >> 1;
                float s = 0.f;
#pragma unroll
                for (int m = 0; m < 4; ++m) {
                    s = fmaf(dd[c + m], W[p + 2 * m], s);
                    s = fmaf(aa[c + m], S[p + 2 * m], s);
                }
                out[u] = s;
            }
            const int n0 = 8 * g;
            if (n0 >= PAD0 && n0 + 8 <= PAD0 + MLEN) {
                F4 o0, o1;
                o0.f[0] = out[0]; o0.f[1] = out[1]; o0.f[2] = out[2]; o0.f[3] = out[3];
                o1.f[0] = out[4]; o1.f[1] = out[5]; o1.f[2] = out[6]; o1.f[3] = out[7];
                float4* r4 = reinterpret_cast<float4*>(ro + (n0 - PAD0));
                r4[0] = o0.v; r4[1] = o1.v;
            } else {
#pragma unroll
                for (int u = 0; u < 8; ++u) {
                    const int n = n0 + u;
                    if (n >= PAD0 && n < PAD0 + MLEN) ro[n - PAD0] = out[u];
                }
            }
        }
    }
}

extern "C" void kernel_launch(void* const* d_in, const int* in_sizes, int n_in,
                              void* d_out, int out_size, void* d_ws, size_t ws_size,
                              hipStream_t stream) {
    const float* x           = (const float*)d_in[0];
    const float* scaling     = (const float*)d_in[1];
    const float* scaling_rec = (const float*)d_in[2];
    float* recon = (float*)d_out;                       // 2048*3000 floats
    float* coefo = recon + (size_t)NROWS * MLEN;        // 2048*4096 floats
    despawn_kernel<<<dim3(NROWS), dim3(NT), 0, stream>>>(x, scaling, scaling_rec,
                                                         recon, coefo);
    (void)in_sizes; (void)n_in; (void)out_size; (void)d_ws; (void)ws_size;
}